// Round 2
// baseline (9438.985 us; speedup 1.0000x reference)
//
#include <hip/hip_runtime.h>
#include <hip/hip_bf16.h>

static constexpr int H   = 1024;
static constexpr int LNUM = 4;
static constexpr int SEQ = 2048;
static constexpr int BATCH = 2;
static constexpr int TOK = BATCH * SEQ;   // 4096 tokens
static constexpr int NI  = 4096;          // MLP inner
static constexpr int QKVD = H + 128;      // 1152

// ---------------------------------------------------------------- embedding
__global__ __launch_bounds__(256) void embed_kernel(
    const int* __restrict__ ids, const int* __restrict__ pos,
    const float* __restrict__ wte, const float* __restrict__ wpe,
    float* __restrict__ h) {
  int i = blockIdx.x * 256 + threadIdx.x;      // covers TOK*H
  int tok = i >> 10, d = i & 1023;
  h[i] = wte[(size_t)ids[tok] * H + d] + wpe[(size_t)pos[tok] * H + d];
}

// ---------------------------------------------------------------- layernorm
__global__ __launch_bounds__(256) void ln_kernel(
    const float* __restrict__ X, const float* __restrict__ w,
    const float* __restrict__ b, float* __restrict__ out) {
  int row = blockIdx.x;
  const float* x = X + (size_t)row * H;
  int tid = threadIdx.x;
  int lane = tid & 63, wid = tid >> 6;
  float v[4];
#pragma unroll
  for (int i = 0; i < 4; i++) v[i] = x[tid + i * 256];
  float s = v[0] + v[1] + v[2] + v[3];
#pragma unroll
  for (int off = 32; off > 0; off >>= 1) s += __shfl_xor(s, off);
  __shared__ float red[8];
  if (lane == 0) red[wid] = s;
  __syncthreads();
  float mu = (red[0] + red[1] + red[2] + red[3]) * (1.0f / H);
  float q = 0.f;
#pragma unroll
  for (int i = 0; i < 4; i++) { float d = v[i] - mu; q += d * d; }
#pragma unroll
  for (int off = 32; off > 0; off >>= 1) q += __shfl_xor(q, off);
  if (lane == 0) red[4 + wid] = q;
  __syncthreads();
  float var = (red[4] + red[5] + red[6] + red[7]) * (1.0f / H);
  float inv = rsqrtf(var + 1e-5f);
#pragma unroll
  for (int i = 0; i < 4; i++) {
    int col = tid + i * 256;
    out[(size_t)row * H + col] = (v[i] - mu) * inv * w[col] + b[col];
  }
}

// ---------------------------------------------------------------- GEMM: C = A(MxK) * W(NxK)^T + bias
// MODE 0: C = r    MODE 1: C += r (residual into existing C)    MODE 2: C = gelu(r)
template <int MODE>
__global__ __launch_bounds__(256) void gemm_bt(
    const float* __restrict__ A, const float* __restrict__ W,
    const float* __restrict__ bias, float* __restrict__ C,
    int M, int N, int K) {
  __shared__ float As[16][68];   // [k][m], pad 4 keeps float4 alignment, 2-way banks (free)
  __shared__ float Ws[16][68];   // [k][n]
  int tid = threadIdx.x;
  int tx = tid & 15, ty = tid >> 4;
  int row0 = blockIdx.y * 64, col0 = blockIdx.x * 64;
  int kk = tid & 15, rr = tid >> 4;
  float acc[4][4] = {};
  const float* Abase = A + (size_t)row0 * K;
  const float* Wbase = W + (size_t)col0 * K;
  for (int k0 = 0; k0 < K; k0 += 16) {
#pragma unroll
    for (int r = 0; r < 4; r++) {
      int m = rr + r * 16;
      As[kk][m] = Abase[(size_t)m * K + k0 + kk];
      Ws[kk][m] = Wbase[(size_t)m * K + k0 + kk];
    }
    __syncthreads();
#pragma unroll
    for (int k = 0; k < 16; k++) {
      float av[4], bv[4];
      *(float4*)av = *(const float4*)&As[k][ty * 4];
      *(float4*)bv = *(const float4*)&Ws[k][tx * 4];
#pragma unroll
      for (int i = 0; i < 4; i++)
#pragma unroll
        for (int j = 0; j < 4; j++) acc[i][j] += av[i] * bv[j];
    }
    __syncthreads();
  }
#pragma unroll
  for (int i = 0; i < 4; i++) {
    int m = row0 + ty * 4 + i;
#pragma unroll
    for (int j = 0; j < 4; j++) {
      int n = col0 + tx * 4 + j;
      float r = acc[i][j] + bias[n];
      size_t idx = (size_t)m * N + n;
      if (MODE == 1) r += C[idx];
      if (MODE == 2) r = 0.5f * r * (1.0f + erff(r * 0.70710678118654752f));
      C[idx] = r;
    }
  }
}

// ---------------------------------------------------------------- MQA attention
// qkv: [TOK][1152] f32 (q 0..1023 as n*64+d, k 1024..1087, v 1088..1151)
// out: [TOK][1024] f32.  Block = 1024 thr = 16 waves (one per head) for one (b,s).
__global__ __launch_bounds__(1024) void mqa_attn(
    const float* __restrict__ qkv, float* __restrict__ out) {
  int s = blockIdx.x, b = blockIdx.y;
  int wave = threadIdx.x >> 6, lane = threadIdx.x & 63;
  __shared__ float Kc[64][65];
  __shared__ float Vc[64][65];
  __shared__ float qs[16][64];
  __shared__ float ps[16][64];
  const size_t base = ((size_t)b * SEQ + s) * QKVD;
  qs[wave][lane] = qkv[base + threadIdx.x];   // q layout == tid
  float m = -1e30f, l = 0.f, o = 0.f;
  int nch = (s >> 6) + 1;
  for (int c = 0; c < nch; c++) {
    int t0 = c << 6;
    __syncthreads();   // prev chunk fully consumed before overwrite (also covers qs init)
#pragma unroll
    for (int i = 0; i < 4; i++) {
      int e = threadIdx.x + (i << 10);
      int r = e >> 6, d = e & 63;
      size_t g = ((size_t)b * SEQ + t0 + r) * QKVD;
      Kc[r][d] = qkv[g + 1024 + d];
      Vc[r][d] = qkv[g + 1088 + d];
    }
    __syncthreads();
    // scores: lane handles t = t0 + lane
    float sc = 0.f;
#pragma unroll
    for (int d = 0; d < 64; d++) sc += qs[wave][d] * Kc[lane][d];
    int t = t0 + lane;
    sc = (t <= s) ? sc * 0.125f : -1e30f;   // net scale = 1/sqrt(64)
    float cmax = sc;
#pragma unroll
    for (int off = 32; off > 0; off >>= 1) cmax = fmaxf(cmax, __shfl_xor(cmax, off));
    float mn = fmaxf(m, cmax);
    float p = __expf(sc - mn);              // masked lanes underflow to 0
    float alpha = __expf(m - mn);
    float psum = p;
#pragma unroll
    for (int off = 32; off > 0; off >>= 1) psum += __shfl_xor(psum, off);
    l = l * alpha + psum;
    m = mn;
    ps[wave][lane] = p;
    __syncthreads();                        // ps visible (and keeps waves in step)
    float acc = 0.f;
#pragma unroll
    for (int j = 0; j < 64; j++) acc += ps[wave][j] * Vc[j][lane];
    o = o * alpha + acc;
  }
  out[((size_t)b * SEQ + s) * H + threadIdx.x] = o / l;
}

// ---------------------------------------------------------------- launch
extern "C" void kernel_launch(void* const* d_in, const int* in_sizes, int n_in,
                              void* d_out, int out_size, void* d_ws, size_t ws_size,
                              hipStream_t stream) {
  const int*   input_ids    = (const int*)d_in[0];
  const int*   position_ids = (const int*)d_in[1];
  const float* wte     = (const float*)d_in[2];
  const float* wpe     = (const float*)d_in[3];
  const float* ln1_w   = (const float*)d_in[4];
  const float* ln1_b   = (const float*)d_in[5];
  const float* cattn_w = (const float*)d_in[6];
  const float* cattn_b = (const float*)d_in[7];
  const float* cproj_w = (const float*)d_in[8];
  const float* cproj_b = (const float*)d_in[9];
  const float* ln2_w   = (const float*)d_in[10];
  const float* ln2_b   = (const float*)d_in[11];
  const float* fc_w    = (const float*)d_in[12];
  const float* fc_b    = (const float*)d_in[13];
  const float* mproj_w = (const float*)d_in[14];
  const float* mproj_b = (const float*)d_in[15];
  const float* lnf_w   = (const float*)d_in[16];
  const float* lnf_b   = (const float*)d_in[17];

  float* ws = (float*)d_ws;
  float* h    = ws;                       // TOK*H
  float* x    = ws + (size_t)TOK * H;     // TOK*H (ln out, then attn out)
  float* big  = ws + (size_t)2 * TOK * H; // max(TOK*QKVD, TOK*NI) = TOK*NI
  float* qkv   = big;
  float* fcact = big;

  embed_kernel<<<TOK * H / 256, 256, 0, stream>>>(input_ids, position_ids, wte, wpe, h);

  for (int l = 0; l < LNUM; l++) {
    ln_kernel<<<TOK, 256, 0, stream>>>(h, ln1_w + l * H, ln1_b + l * H, x);
    gemm_bt<0><<<dim3(QKVD / 64, TOK / 64), 256, 0, stream>>>(
        x, cattn_w + (size_t)l * QKVD * H, cattn_b + l * QKVD, qkv, TOK, QKVD, H);
    mqa_attn<<<dim3(SEQ, BATCH), 1024, 0, stream>>>(qkv, x);
    gemm_bt<1><<<dim3(H / 64, TOK / 64), 256, 0, stream>>>(
        x, cproj_w + (size_t)l * H * H, cproj_b + l * H, h, TOK, H, H);
    ln_kernel<<<TOK, 256, 0, stream>>>(h, ln2_w + l * H, ln2_b + l * H, x);
    gemm_bt<2><<<dim3(NI / 64, TOK / 64), 256, 0, stream>>>(
        x, fc_w + (size_t)l * NI * H, fc_b + l * NI, fcact, TOK, NI, H);
    gemm_bt<1><<<dim3(H / 64, TOK / 64), 256, 0, stream>>>(
        fcact, mproj_w + (size_t)l * H * NI, mproj_b + l * H, h, TOK, H, NI);
  }
  ln_kernel<<<TOK, 256, 0, stream>>>(h, lnf_w, lnf_b, (float*)d_out);
}

// Round 3
// 1957.858 us; speedup vs baseline: 4.8211x; 4.8211x over previous
//
#include <hip/hip_runtime.h>
#include <math.h>

typedef __attribute__((ext_vector_type(8))) short short8;
typedef __attribute__((ext_vector_type(8))) __bf16 bf16x8;
typedef __attribute__((ext_vector_type(4))) float f32x4;

static constexpr int H = 1024, LNUM = 4, SEQ = 2048, BATCH = 2;
static constexpr int TOK = BATCH * SEQ;       // 4096
static constexpr int NI = 4096, QKVD = H + 128; // 1152

__device__ __forceinline__ short f2bf(float f) {   // RNE fp32->bf16 bits
  union { float f; unsigned u; } c; c.f = f;
  return (short)((c.u + 0x7fffu + ((c.u >> 16) & 1u)) >> 16);
}

__device__ __forceinline__ void gl_lds16(const short* g, short* l) {
  __builtin_amdgcn_global_load_lds(
      (const __attribute__((address_space(1))) unsigned*)g,
      (__attribute__((address_space(3))) unsigned*)l, 16, 0, 0);
}

#define MFMA16(a, b, c) __builtin_amdgcn_mfma_f32_16x16x32_bf16(a, b, c, 0, 0, 0)

// ---------------------------------------------------------------- embedding
__global__ __launch_bounds__(256) void embed_kernel(
    const int* __restrict__ ids, const int* __restrict__ pos,
    const float* __restrict__ wte, const float* __restrict__ wpe,
    float* __restrict__ h) {
  int i = blockIdx.x * 256 + threadIdx.x;
  int tok = i >> 10, d = i & 1023;
  h[i] = wte[(size_t)ids[tok] * H + d] + wpe[(size_t)pos[tok] * H + d];
}

// ---------------------------------------------------------------- fp32 -> bf16 cast (weights)
__global__ __launch_bounds__(256) void cast_kernel(
    const float* __restrict__ src, short* __restrict__ dst) {
  int i = blockIdx.x * 256 + threadIdx.x;
  float4 v = ((const float4*)src)[i];
  union { short s[4]; uint2 u; } p;
  p.s[0] = f2bf(v.x); p.s[1] = f2bf(v.y); p.s[2] = f2bf(v.z); p.s[3] = f2bf(v.w);
  ((uint2*)dst)[i] = p.u;
}

// ---------------------------------------------------------------- layernorm (fp32 in; bf16 or fp32 out)
template <bool BF16_OUT>
__global__ __launch_bounds__(256) void ln_kernel(
    const float* __restrict__ X, const float* __restrict__ w,
    const float* __restrict__ b, void* __restrict__ out) {
  int row = blockIdx.x;
  const float* x = X + (size_t)row * H;
  int tid = threadIdx.x, lane = tid & 63, wid = tid >> 6;
  float v[4];
#pragma unroll
  for (int i = 0; i < 4; i++) v[i] = x[tid + i * 256];
  float s = v[0] + v[1] + v[2] + v[3];
#pragma unroll
  for (int off = 32; off > 0; off >>= 1) s += __shfl_xor(s, off);
  __shared__ float red[8];
  if (lane == 0) red[wid] = s;
  __syncthreads();
  float mu = (red[0] + red[1] + red[2] + red[3]) * (1.0f / H);
  float q = 0.f;
#pragma unroll
  for (int i = 0; i < 4; i++) { float d = v[i] - mu; q += d * d; }
#pragma unroll
  for (int off = 32; off > 0; off >>= 1) q += __shfl_xor(q, off);
  if (lane == 0) red[4 + wid] = q;
  __syncthreads();
  float var = (red[4] + red[5] + red[6] + red[7]) * (1.0f / H);
  float inv = rsqrtf(var + 1e-5f);
#pragma unroll
  for (int i = 0; i < 4; i++) {
    int col = tid + i * 256;
    float r = (v[i] - mu) * inv * w[col] + b[col];
    if (BF16_OUT) ((short*)out)[(size_t)row * H + col] = f2bf(r);
    else          ((float*)out)[(size_t)row * H + col] = r;
  }
}

// ---------------------------------------------------------------- MFMA GEMM: C = A(M,K)bf16 * W(N,K)bf16^T + bias(f32)
// MODE 0: C(bf16) = r   MODE 1: C(f32) += r   MODE 2: C(bf16) = gelu(r)
// 128x128 tile, BK=32, 256 thr = 4 waves in 2x2 of 64x64; wave: 4x4 tiles of 16x16.
template <int MODE>
__global__ __launch_bounds__(256) void gemm_mfma(
    const short* __restrict__ A, const short* __restrict__ W,
    const float* __restrict__ bias, void* __restrict__ Cv,
    int M, int N, int K) {
  __shared__ short As[128 * 32];
  __shared__ short Bs[128 * 32];
  int tid = threadIdx.x, wave = tid >> 6, lane = tid & 63;
  int li = lane & 15, lg = lane >> 4;
  int row0 = blockIdx.y * 128, col0 = blockIdx.x * 128;
  int wm = (wave & 1) * 64, wn = (wave >> 1) * 64;
  f32x4 acc[4][4] = {};
  const short* Ab = A + (size_t)(row0 + (tid >> 2)) * K + (tid & 3) * 8;
  const short* Wb = W + (size_t)(col0 + (tid >> 2)) * K + (tid & 3) * 8;
  for (int k0 = 0; k0 < K; k0 += 32) {
    __syncthreads();                       // LDS free (prev compute done)
    gl_lds16(Ab + k0,            As + tid * 8);
    gl_lds16(Ab + k0 + 64 * K,   As + 2048 + tid * 8);
    gl_lds16(Wb + k0,            Bs + tid * 8);
    gl_lds16(Wb + k0 + 64 * K,   Bs + 2048 + tid * 8);
    __syncthreads();                       // drains vmcnt before barrier
    bf16x8 af[4], bfr[4];
#pragma unroll
    for (int i = 0; i < 4; ++i) {
      af[i]  = *(const bf16x8*)&As[(wm + i * 16 + li) * 32 + lg * 8];
      bfr[i] = *(const bf16x8*)&Bs[(wn + i * 16 + li) * 32 + lg * 8];
    }
#pragma unroll
    for (int i = 0; i < 4; ++i)
#pragma unroll
      for (int j = 0; j < 4; ++j) acc[i][j] = MFMA16(af[i], bfr[j], acc[i][j]);
  }
  // epilogue; C/D layout: col = li, row = lg*4 + reg
  float* Cf = (float*)Cv;
  short* Cs = (short*)Cv;
#pragma unroll
  for (int i = 0; i < 4; ++i) {
    int gr = row0 + wm + i * 16 + lg * 4;
#pragma unroll
    for (int j = 0; j < 4; ++j) {
      int gc = col0 + wn + j * 16 + li;
      float bv = bias[gc];
#pragma unroll
      for (int r = 0; r < 4; ++r) {
        float v = acc[i][j][r] + bv;
        size_t idx = (size_t)(gr + r) * N + gc;
        if (MODE == 1) {
          Cf[idx] += v;
        } else if (MODE == 2) {
          v = 0.5f * v * (1.0f + erff(v * 0.70710678118654752f));
          Cs[idx] = f2bf(v);
        } else {
          Cs[idx] = f2bf(v);
        }
      }
    }
  }
}

// ---------------------------------------------------------------- MFMA flash MQA attention
// qkv bf16 [TOK][1152]; out bf16 [TOK][1024]. Block 256 thr = 4 waves.
// Block = (head, qtile of 64 rows, b). Wave w owns q-rows w*16..w*16+15.
__global__ __launch_bounds__(256) void mqa_attn(
    const short* __restrict__ qkv, short* __restrict__ out) {
  int head = blockIdx.x, qt = blockIdx.y, b = blockIdx.z;
  int tid = threadIdx.x, wave = tid >> 6, lane = tid & 63;
  int li = lane & 15, lg = lane >> 4;

  __shared__ short Kc[64 * 72];        // [t][d], row pad 8 -> balanced banks
  __shared__ short VT[64 * 72];        // [d][t], transposed for PV B-frags
  __shared__ short Ps[4 * 16 * 72];    // per-wave P [m][t], row pad 8

  const size_t qrow0 = (size_t)(b * SEQ + qt * 64);
  bf16x8 qf[2];
  {
    const short* qp = qkv + (qrow0 + wave * 16 + li) * QKVD + head * 64 + lg * 8;
    qf[0] = *(const bf16x8*)(qp);
    qf[1] = *(const bf16x8*)(qp + 32);
  }
  f32x4 oacc[4] = {};
  float m_i[4], l_i[4];
#pragma unroll
  for (int r = 0; r < 4; ++r) { m_i[r] = -1e30f; l_i[r] = 0.f; }

  int t_ = tid >> 3, c_ = tid & 7;
  for (int j = 0; j <= qt; ++j) {
    __syncthreads();                  // Kc/VT consumable again
    {
      const short* g0 = qkv + ((size_t)(b * SEQ + j * 64 + t_)) * QKVD;
      const short* g1 = g0 + 32 * QKVD;
      short8 k0 = *(const short8*)(g0 + 1024 + c_ * 8);
      short8 k1 = *(const short8*)(g1 + 1024 + c_ * 8);
      short8 v0 = *(const short8*)(g0 + 1088 + c_ * 8);
      short8 v1 = *(const short8*)(g1 + 1088 + c_ * 8);
      *(short8*)&Kc[t_ * 72 + c_ * 8] = k0;
      *(short8*)&Kc[(t_ + 32) * 72 + c_ * 8] = k1;
#pragma unroll
      for (int e = 0; e < 8; ++e) {
        VT[(c_ * 8 + e) * 72 + t_] = v0[e];
        VT[(c_ * 8 + e) * 72 + t_ + 32] = v1[e];
      }
    }
    __syncthreads();

    // S = Q K^T (wave's 16 rows x 64 keys)
    f32x4 s[4];
#pragma unroll
    for (int n = 0; n < 4; ++n) {
      bf16x8 kf0 = *(const bf16x8*)&Kc[(n * 16 + li) * 72 + lg * 8];
      bf16x8 kf1 = *(const bf16x8*)&Kc[(n * 16 + li) * 72 + 32 + lg * 8];
      f32x4 a = {};
      a = MFMA16(qf[0], kf0, a);
      a = MFMA16(qf[1], kf1, a);
      s[n] = a;
    }
    // scale + causal mask (only diagonal chunk needs mask)
    bool diag = (j == qt);
#pragma unroll
    for (int n = 0; n < 4; ++n)
#pragma unroll
      for (int r = 0; r < 4; ++r) {
        float v = s[n][r] * 0.125f;
        if (diag && (n * 16 + li) > (wave * 16 + lg * 4 + r)) v = -1e30f;
        s[n][r] = v;
      }
    // online softmax per row (row = lg*4 + r, spread over 16 lanes of group lg)
    float alpha[4];
#pragma unroll
    for (int r = 0; r < 4; ++r) {
      float mx = fmaxf(fmaxf(s[0][r], s[1][r]), fmaxf(s[2][r], s[3][r]));
#pragma unroll
      for (int off = 1; off < 16; off <<= 1) mx = fmaxf(mx, __shfl_xor(mx, off));
      float mn = fmaxf(m_i[r], mx);
      alpha[r] = __expf(m_i[r] - mn);
      m_i[r] = mn;
      float ps = 0.f;
#pragma unroll
      for (int n = 0; n < 4; ++n) {
        float p = __expf(s[n][r] - mn);
        s[n][r] = p;
        ps += p;
      }
#pragma unroll
      for (int off = 1; off < 16; off <<= 1) ps += __shfl_xor(ps, off);
      l_i[r] = l_i[r] * alpha[r] + ps;
    }
    // rescale O, stash P (bf16) in LDS for A-frag reads
#pragma unroll
    for (int dn = 0; dn < 4; ++dn)
#pragma unroll
      for (int r = 0; r < 4; ++r) oacc[dn][r] *= alpha[r];
    short* pw = Ps + wave * 1152;
#pragma unroll
    for (int n = 0; n < 4; ++n)
#pragma unroll
      for (int r = 0; r < 4; ++r) pw[(lg * 4 + r) * 72 + n * 16 + li] = f2bf(s[n][r]);
    // O += P V   (A=P[m][t], B=V[t][d] via VT)
#pragma unroll
    for (int ks = 0; ks < 2; ++ks) {
      bf16x8 pf = *(const bf16x8*)&pw[li * 72 + ks * 32 + lg * 8];
#pragma unroll
      for (int dn = 0; dn < 4; ++dn) {
        bf16x8 vf = *(const bf16x8*)&VT[(dn * 16 + li) * 72 + ks * 32 + lg * 8];
        oacc[dn] = MFMA16(pf, vf, oacc[dn]);
      }
    }
  }
#pragma unroll
  for (int r = 0; r < 4; ++r) {
    float inv = 1.0f / l_i[r];
    size_t row = (qrow0 + wave * 16 + lg * 4 + r) * H + head * 64;
#pragma unroll
    for (int dn = 0; dn < 4; ++dn) out[row + dn * 16 + li] = f2bf(oacc[dn][r] * inv);
  }
}

// ---------------------------------------------------------------- launch
extern "C" void kernel_launch(void* const* d_in, const int* in_sizes, int n_in,
                              void* d_out, int out_size, void* d_ws, size_t ws_size,
                              hipStream_t stream) {
  const int*   input_ids    = (const int*)d_in[0];
  const int*   position_ids = (const int*)d_in[1];
  const float* wte     = (const float*)d_in[2];
  const float* wpe     = (const float*)d_in[3];
  const float* ln1_w   = (const float*)d_in[4];
  const float* ln1_b   = (const float*)d_in[5];
  const float* cattn_w = (const float*)d_in[6];
  const float* cattn_b = (const float*)d_in[7];
  const float* cproj_w = (const float*)d_in[8];
  const float* cproj_b = (const float*)d_in[9];
  const float* ln2_w   = (const float*)d_in[10];
  const float* ln2_b   = (const float*)d_in[11];
  const float* fc_w    = (const float*)d_in[12];
  const float* fc_b    = (const float*)d_in[13];
  const float* mproj_w = (const float*)d_in[14];
  const float* mproj_b = (const float*)d_in[15];
  const float* lnf_w   = (const float*)d_in[16];
  const float* lnf_b   = (const float*)d_in[17];

  float* h     = (float*)d_ws;                    // TOK*H f32
  short* xbf   = (short*)(h + (size_t)TOK * H);   // TOK*H bf16 (ln out / attn out)
  short* qkvbf = xbf + (size_t)TOK * H;           // TOK*QKVD bf16
  short* fcbf  = qkvbf + (size_t)TOK * QKVD;      // TOK*NI bf16
  short* wqkv  = fcbf + (size_t)TOK * NI;         // per-layer bf16 weights
  short* wcp   = wqkv + (size_t)QKVD * H;
  short* wfc   = wcp + (size_t)H * H;
  short* wmp   = wfc + (size_t)NI * H;

  embed_kernel<<<TOK * H / 256, 256, 0, stream>>>(input_ids, position_ids, wte, wpe, h);

  for (int l = 0; l < LNUM; l++) {
    cast_kernel<<<QKVD * H / 1024, 256, 0, stream>>>(cattn_w + (size_t)l * QKVD * H, wqkv);
    cast_kernel<<<H * H / 1024, 256, 0, stream>>>(cproj_w + (size_t)l * H * H, wcp);
    cast_kernel<<<NI * H / 1024, 256, 0, stream>>>(fc_w + (size_t)l * NI * H, wfc);
    cast_kernel<<<H * NI / 1024, 256, 0, stream>>>(mproj_w + (size_t)l * H * NI, wmp);

    ln_kernel<true><<<TOK, 256, 0, stream>>>(h, ln1_w + l * H, ln1_b + l * H, xbf);
    gemm_mfma<0><<<dim3(QKVD / 128, TOK / 128), 256, 0, stream>>>(
        xbf, wqkv, cattn_b + (size_t)l * QKVD, qkvbf, TOK, QKVD, H);
    mqa_attn<<<dim3(16, 32, BATCH), 256, 0, stream>>>(qkvbf, xbf);
    gemm_mfma<1><<<dim3(H / 128, TOK / 128), 256, 0, stream>>>(
        xbf, wcp, cproj_b + (size_t)l * H, h, TOK, H, H);
    ln_kernel<true><<<TOK, 256, 0, stream>>>(h, ln2_w + l * H, ln2_b + l * H, xbf);
    gemm_mfma<2><<<dim3(NI / 128, TOK / 128), 256, 0, stream>>>(
        xbf, wfc, fc_b + (size_t)l * NI, fcbf, TOK, NI, H);
    gemm_mfma<1><<<dim3(H / 128, TOK / 128), 256, 0, stream>>>(
        fcbf, wmp, mproj_b + (size_t)l * H, h, TOK, H, NI);
  }
  ln_kernel<false><<<TOK, 256, 0, stream>>>(h, lnf_w, lnf_b, d_out);
}